// Round 13
// baseline (647.448 us; speedup 1.0000x reference)
//
#include <hip/hip_runtime.h>
#include <stdint.h>

#define KCAPS 10
#define OC    16
#define IC    256
#define HWSZ  36
#define PRIM  72
#define PD    8
#define EDIM  16
#define BMAX  2048

typedef short bf16x8 __attribute__((ext_vector_type(8)));
typedef float f32x4  __attribute__((ext_vector_type(4)));

// persistent prepped data (recomputed every launch -> deterministic)
__device__ unsigned short g_whi[KCAPS * OC * IC];
__device__ unsigned short g_wlo[KCAPS * OC * IC];
__device__ float          g_wtsT[KCAPS * PRIM * EDIM * PD];   // [k][p][e][d]
__device__ float          g_caps_fallback[(size_t)BMAX * 160 * HWSZ];

// gemm2 LDS (76032 B), 2 batch elements, shorts:
//   b0: xsh [0,9504) xsl [9504,19008) ; b1: xsh [19008,28512) xsl [28512,38016)
//   each plane bf16 [36][264]; n-tiles based at hw {0,16,20} -> no OOB slack needed
#define SMEM_G 76032

__device__ __forceinline__ void bf_split(float v, unsigned short& hb, unsigned short& lb) {
    __bf16 h = (__bf16)v;
    hb = __builtin_bit_cast(unsigned short, h);
    __bf16 l = (__bf16)(v - (float)h);
    lb = __builtin_bit_cast(unsigned short, l);
}

__device__ __forceinline__ f32x4 mfma16(bf16x8 a, bf16x8 b, f32x4 c) {
    return __builtin_amdgcn_mfma_f32_16x16x32_bf16(a, b, c, 0, 0, 0);
}

__global__ __launch_bounds__(256)
void prep_kernel(const float* __restrict__ w, const float* __restrict__ wts) {
    int i = blockIdx.x * 256 + threadIdx.x;
    if (i < KCAPS * OC * IC) {                 // 40960
        unsigned short hb, lb;
        bf_split(w[i], hb, lb);
        g_whi[i] = hb;
        g_wlo[i] = lb;
    }
    if (i < KCAPS * PRIM * EDIM * PD) {        // 92160: [kp][e][d] <- [kp][d][e]
        int d = i & 7, e = (i >> 3) & 15, kp = i >> 7;
        g_wtsT[i] = wts[(size_t)kp * 128 + d * 16 + e];
    }
}

// ---- gemm2: 2 batch elements per block, fused transpose, dual accumulators
__global__ __launch_bounds__(256, 2)
void gemm_caps(const float* __restrict__ x, const float* __restrict__ conv_b,
               float* __restrict__ caps_g) {
    extern __shared__ char smem[];
    uint32_t* xs_u = (uint32_t*)smem;
    const short* xs_s = (const short*)smem;

    const int t  = threadIdx.x;
    const int bb = blockIdx.x;
    const int wv = t >> 6;            // 4 waves; wave wv -> m-tiles {wv, wv+4[, wv+8]}
    const int ln = t & 63;
    const int row = ln & 15;
    const int g   = ln >> 4;
    const int nm  = (wv < 2) ? 3 : 2;

    // stage BOTH elements transposed -> bf16 hi/lo [36][264]
    for (int task = t; task < 2304; task += 256) {
        int half = (task >= 1152) ? 1 : 0;
        int tt = task - half * 1152;
        int cp = tt / 9, hq = tt - cp * 9;
        const float4* x4 = (const float4*)(x + (size_t)(2 * bb + half) * (IC * HWSZ));
        float4 va = x4[(2 * cp) * 9 + hq];
        float4 vb = x4[(2 * cp + 1) * 9 + hq];
        uint32_t* xh = xs_u + half * 9504;
        uint32_t* xl = xh + 4752;
        int base = (4 * hq) * 132 + cp;
        unsigned short ha, la, hb, lb;
        bf_split(va.x, ha, la); bf_split(vb.x, hb, lb);
        xh[base]       = (uint32_t)ha | ((uint32_t)hb << 16);
        xl[base]       = (uint32_t)la | ((uint32_t)lb << 16);
        bf_split(va.y, ha, la); bf_split(vb.y, hb, lb);
        xh[base + 132] = (uint32_t)ha | ((uint32_t)hb << 16);
        xl[base + 132] = (uint32_t)la | ((uint32_t)lb << 16);
        bf_split(va.z, ha, la); bf_split(vb.z, hb, lb);
        xh[base + 264] = (uint32_t)ha | ((uint32_t)hb << 16);
        xl[base + 264] = (uint32_t)la | ((uint32_t)lb << 16);
        bf_split(va.w, ha, la); bf_split(vb.w, hb, lb);
        xh[base + 396] = (uint32_t)ha | ((uint32_t)hb << 16);
        xl[base + 396] = (uint32_t)la | ((uint32_t)lb << 16);
    }
    __syncthreads();

    const int hwbase[3] = {0, 16, 20};

    f32x4 acc0[3][3] = {}, acc1[3][3] = {};
    for (int kt = 0; kt < 8; ++kt) {
        bf16x8 bh[3], bl[3];
        #pragma unroll
        for (int mi = 0; mi < 3; ++mi) {
            if (mi < nm) {
                int woff = ((wv + 4 * mi) * 16 + row) * 256 + kt * 32 + g * 8;
                bh[mi] = *(const bf16x8*)(g_whi + woff);
                bl[mi] = *(const bf16x8*)(g_wlo + woff);
            }
        }
        bf16x8 ah0[3], al0[3], ah1[3], al1[3];
        #pragma unroll
        for (int nt = 0; nt < 3; ++nt) {
            int o2 = (hwbase[nt] + row) * 264 + kt * 32 + g * 8;
            ah0[nt] = *(const bf16x8*)(xs_s + o2);
            al0[nt] = *(const bf16x8*)(xs_s + 9504 + o2);
            ah1[nt] = *(const bf16x8*)(xs_s + 19008 + o2);
            al1[nt] = *(const bf16x8*)(xs_s + 28512 + o2);
        }
        #pragma unroll
        for (int mi = 0; mi < 3; ++mi) {
            if (mi < nm) {
                #pragma unroll
                for (int nt = 0; nt < 3; ++nt) {
                    acc0[mi][nt] = mfma16(ah0[nt], bh[mi], acc0[mi][nt]);
                    acc1[mi][nt] = mfma16(ah1[nt], bh[mi], acc1[mi][nt]);
                    acc0[mi][nt] = mfma16(al0[nt], bh[mi], acc0[mi][nt]);
                    acc1[mi][nt] = mfma16(al1[nt], bh[mi], acc1[mi][nt]);
                    acc0[mi][nt] = mfma16(ah0[nt], bl[mi], acc0[mi][nt]);
                    acc1[mi][nt] = mfma16(ah1[nt], bl[mi], acc1[mi][nt]);
                }
            }
        }
    }

    // C-write (+bias): hw = hwbase[nt]+g*4+r ; tile2 writes only g==3 (hw 32-35)
    float* cg0 = caps_g + (size_t)(2 * bb) * (160 * HWSZ);
    float* cg1 = caps_g + (size_t)(2 * bb + 1) * (160 * HWSZ);
    #pragma unroll
    for (int mi = 0; mi < 3; ++mi) {
        if (mi < nm) {
            int m = (wv + 4 * mi) * 16 + row;
            float bias = conv_b[m];
            #pragma unroll
            for (int nt = 0; nt < 3; ++nt) {
                int hw0 = hwbase[nt] + g * 4;
                if (nt < 2 || g == 3) {
                    float4 o0, o1;
                    o0.x = acc0[mi][nt][0] + bias; o1.x = acc1[mi][nt][0] + bias;
                    o0.y = acc0[mi][nt][1] + bias; o1.y = acc1[mi][nt][1] + bias;
                    o0.z = acc0[mi][nt][2] + bias; o1.z = acc1[mi][nt][2] + bias;
                    o0.w = acc0[mi][nt][3] + bias; o1.w = acc1[mi][nt][3] + bias;
                    *(float4*)(cg0 + m * HWSZ + hw0) = o0;
                    *(float4*)(cg1 + m * HWSZ + hw0) = o1;
                }
            }
        }
    }
}

// ---- route_reg: 1 b per block, u in registers, shuffle routing (R6 machinery)
#define SQUASH_V(S, V) { float q_=(S)*(S); q_+=__shfl_xor(q_,1); q_+=__shfl_xor(q_,2); \
    q_+=__shfl_xor(q_,4); q_+=__shfl_xor(q_,8); (V)=(S)*(q_/(1.f+q_))*rsqrtf(q_+1e-8f); }

#define CHAIN_U(UR, PART, KC) { float pa_=0.f; \
    _Pragma("unroll") for (int p4=0;p4<18;++p4){ int p_=4*p4+pr; \
        const float4* cp4_=(const float4*)(cgb + (KC)*576 + p_*8); \
        float4 c0_=cp4_[0], c1_=cp4_[1]; \
        const float4* wq_=(const float4*)(g_wtsT + ((size_t)((KC)*PRIM+p_)*16+e)*8); \
        float4 w0_=wq_[0], w1_=wq_[1]; \
        float a_=c0_.x*w0_.x; a_=fmaf(c0_.y,w0_.y,a_); a_=fmaf(c0_.z,w0_.z,a_); a_=fmaf(c0_.w,w0_.w,a_); \
        a_=fmaf(c1_.x,w1_.x,a_); a_=fmaf(c1_.y,w1_.y,a_); a_=fmaf(c1_.z,w1_.z,a_); a_=fmaf(c1_.w,w1_.w,a_); \
        UR[p4]=a_; pa_+=a_; } (PART)=pa_; }

#define ITER1_CHAIN(UR, PART, KC, V) { \
    float s_=(PART)+__shfl_xor((PART),16); s_+=__shfl_xor(s_,32); s_*=0.1f; SQUASH_V(s_,V); \
    _Pragma("unroll") for (int p4=0;p4<18;++p4){ float d_=UR[p4]*(V); \
        d_+=__shfl_xor(d_,1); d_+=__shfl_xor(d_,2); d_+=__shfl_xor(d_,4); d_+=__shfl_xor(d_,8); \
        if (e==0) b_s[(KC)*PRIM+4*p4+pr]=d_; } }

#define SSUM_CHAIN(UR, KC, V) { float pa_=0.f; \
    _Pragma("unroll") for (int p4=0;p4<18;++p4) pa_=fmaf(c_s[(KC)*PRIM+4*p4+pr],UR[p4],pa_); \
    float s_=pa_+__shfl_xor(pa_,16); s_+=__shfl_xor(s_,32); SQUASH_V(s_,V); }

#define AGREE_CHAIN(UR, KC, V) { \
    _Pragma("unroll") for (int p4=0;p4<18;++p4){ float d_=UR[p4]*(V); \
        d_+=__shfl_xor(d_,1); d_+=__shfl_xor(d_,2); d_+=__shfl_xor(d_,4); d_+=__shfl_xor(d_,8); \
        if (e==0) b_s[(KC)*PRIM+4*p4+pr]+=d_; } }

__global__ __launch_bounds__(256, 4)
void route_reg(const float* __restrict__ caps_g, float* __restrict__ out) {
    __shared__ float b_s[720];
    __shared__ float c_s[720];

    const int t  = threadIdx.x;
    const int bb = blockIdx.x;
    const int wv = t >> 6;            // wave wv owns capsules {wv, wv+4[, wv+8]}
    const int ln = t & 63;
    const int e  = ln & 15;
    const int pr = ln >> 4;
    const bool three = (wv < 2);
    const int kA = wv, kB2 = wv + 4, kC = wv + 8;

    const float* cgb = caps_g + (size_t)bb * (160 * HWSZ);

    float uA[18], uB[18], uC[18];
    float partA, partB, partC = 0.f;
    CHAIN_U(uA, partA, kA);
    CHAIN_U(uB, partB, kB2);
    if (three) { CHAIN_U(uC, partC, kC); }

    float vA, vB, vC = 0.f;
    ITER1_CHAIN(uA, partA, kA, vA);
    ITER1_CHAIN(uB, partB, kB2, vB);
    if (three) { ITER1_CHAIN(uC, partC, kC, vC); }

    #pragma unroll
    for (int it = 1; it < 3; ++it) {
        __syncthreads();              // b_s writes visible; prev c_s reads done
        if (t < PRIM) {               // softmax over k per primary p = t
            float bv[KCAPS];
            float m = -1e30f;
            #pragma unroll
            for (int k2 = 0; k2 < KCAPS; ++k2) { bv[k2] = b_s[k2 * PRIM + t]; m = fmaxf(m, bv[k2]); }
            float sum = 0.f;
            #pragma unroll
            for (int k2 = 0; k2 < KCAPS; ++k2) { bv[k2] = __expf(bv[k2] - m); sum += bv[k2]; }
            float inv = 1.f / sum;
            #pragma unroll
            for (int k2 = 0; k2 < KCAPS; ++k2) c_s[k2 * PRIM + t] = bv[k2] * inv;
        }
        __syncthreads();              // c_s visible
        SSUM_CHAIN(uA, kA, vA);
        SSUM_CHAIN(uB, kB2, vB);
        if (three) { SSUM_CHAIN(uC, kC, vC); }
        if (it < 2) {
            AGREE_CHAIN(uA, kA, vA);
            AGREE_CHAIN(uB, kB2, vB);
            if (three) { AGREE_CHAIN(uC, kC, vC); }
        }
    }

    if (pr == 0) {
        float* ob = out + (size_t)bb * (KCAPS * EDIM);
        ob[kA * 16 + e]  = vA;
        ob[kB2 * 16 + e] = vB;
        if (three) ob[kC * 16 + e] = vC;
    }
}

extern "C" void kernel_launch(void* const* d_in, const int* in_sizes, int n_in,
                              void* d_out, int out_size, void* d_ws, size_t ws_size,
                              hipStream_t stream) {
    const float* x  = (const float*)d_in[0];
    const float* cw = (const float*)d_in[1];
    const float* cb = (const float*)d_in[2];
    const float* wt = (const float*)d_in[3];
    float* out = (float*)d_out;
    const int B = in_sizes[0] / (IC * HWSZ);   // 2048

    size_t capsNeed = (size_t)B * 160 * HWSZ * sizeof(float);   // 47.2 MB
    float* caps_g = nullptr;
    if (d_ws != nullptr && ws_size >= capsNeed) {
        caps_g = (float*)d_ws;
    } else {
        void* sym = nullptr;
        hipGetSymbolAddress(&sym, HIP_SYMBOL(g_caps_fallback));
        caps_g = (float*)sym;
    }

    hipLaunchKernelGGL(prep_kernel, dim3(360), dim3(256), 0, stream, cw, wt);

    hipFuncSetAttribute(reinterpret_cast<const void*>(&gemm_caps),
                        hipFuncAttributeMaxDynamicSharedMemorySize, SMEM_G);
    hipLaunchKernelGGL(gemm_caps, dim3(B / 2), dim3(256), SMEM_G, stream, x, cb, caps_g);

    hipLaunchKernelGGL(route_reg, dim3(B), dim3(256), 0, stream, caps_g, out);
}

// Round 14
// 95.392 us; speedup vs baseline: 6.7872x; 6.7872x over previous
//
#include <hip/hip_runtime.h>
#include <stdint.h>

#define KCAPS 10
#define OC    16
#define IC    256
#define HWSZ  36
#define PRIM  72
#define PD    8
#define EDIM  16
#define BMAX  2048

typedef short bf16x8 __attribute__((ext_vector_type(8)));
typedef float f32x4  __attribute__((ext_vector_type(4)));

// persistent prepped data (recomputed every launch -> deterministic)
__device__ unsigned short g_whi[KCAPS * OC * IC];
__device__ unsigned short g_wlo[KCAPS * OC * IC];
__device__ float4         g_wtsT4[KCAPS * PD * 4 * PRIM];   // [k][(d*4+e4)][p]
__device__ float          g_caps_fallback[(size_t)BMAX * 160 * HWSZ];

// gemm2 LDS (76032 B), 2 batch elements:
//   b0: xsh [0,9504) xsl [9504,19008) ; b1: xsh [19008,28512) xsl [28512,38016)  (short offsets)
//   each plane bf16 [36][264]; n-tiles based at hw {0,16,20} -> all reads in-bounds
#define SMEM_G 76032
// route LDS: u_t f32[16][724] | b_s[720] | c_s[720] | v_s[160] | scale_s[10] = 52776 B
#define SMEM_B (13194 * 4)

__device__ __forceinline__ void bf_split(float v, unsigned short& hb, unsigned short& lb) {
    __bf16 h = (__bf16)v;
    hb = __builtin_bit_cast(unsigned short, h);
    __bf16 l = (__bf16)(v - (float)h);
    lb = __builtin_bit_cast(unsigned short, l);
}

__device__ __forceinline__ f32x4 mfma16(bf16x8 a, bf16x8 b, f32x4 c) {
    return __builtin_amdgcn_mfma_f32_16x16x32_bf16(a, b, c, 0, 0, 0);
}

__global__ __launch_bounds__(256)
void prep_kernel(const float* __restrict__ w, const float* __restrict__ wts) {
    int i = blockIdx.x * 256 + threadIdx.x;
    if (i < KCAPS * OC * IC) {                 // 40960
        unsigned short hb, lb;
        bf_split(w[i], hb, lb);
        g_whi[i] = hb;
        g_wlo[i] = lb;
    }
    if (i < KCAPS * PD * 4 * PRIM) {           // 23040 float4 tasks
        int p = i % PRIM;
        int r = i / PRIM;
        int e4 = r & 3;
        int d  = (r >> 2) & 7;
        int k  = r >> 5;
        g_wtsT4[i] = *(const float4*)(wts + (size_t)(((k * PRIM + p) * PD + d) * EDIM + e4 * 4));
    }
}

// ---- gemm2: 2 batch elements per block, fused transpose, dual accumulators (R13-measured ~49us)
__global__ __launch_bounds__(256, 2)
void gemm_caps(const float* __restrict__ x, const float* __restrict__ conv_b,
               float* __restrict__ caps_g) {
    extern __shared__ char smem[];
    uint32_t* xs_u = (uint32_t*)smem;
    const short* xs_s = (const short*)smem;

    const int t  = threadIdx.x;
    const int bb = blockIdx.x;
    const int wv = t >> 6;            // 4 waves; wave wv -> m-tiles {wv, wv+4[, wv+8]}
    const int ln = t & 63;
    const int row = ln & 15;
    const int g   = ln >> 4;
    const int nm  = (wv < 2) ? 3 : 2;

    // stage BOTH elements transposed -> bf16 hi/lo [36][264]
    for (int task = t; task < 2304; task += 256) {
        int half = (task >= 1152) ? 1 : 0;
        int tt = task - half * 1152;
        int cp = tt / 9, hq = tt - cp * 9;
        const float4* x4 = (const float4*)(x + (size_t)(2 * bb + half) * (IC * HWSZ));
        float4 va = x4[(2 * cp) * 9 + hq];
        float4 vb = x4[(2 * cp + 1) * 9 + hq];
        uint32_t* xh = xs_u + half * 9504;
        uint32_t* xl = xh + 4752;
        int base = (4 * hq) * 132 + cp;
        unsigned short ha, la, hb, lb;
        bf_split(va.x, ha, la); bf_split(vb.x, hb, lb);
        xh[base]       = (uint32_t)ha | ((uint32_t)hb << 16);
        xl[base]       = (uint32_t)la | ((uint32_t)lb << 16);
        bf_split(va.y, ha, la); bf_split(vb.y, hb, lb);
        xh[base + 132] = (uint32_t)ha | ((uint32_t)hb << 16);
        xl[base + 132] = (uint32_t)la | ((uint32_t)lb << 16);
        bf_split(va.z, ha, la); bf_split(vb.z, hb, lb);
        xh[base + 264] = (uint32_t)ha | ((uint32_t)hb << 16);
        xl[base + 264] = (uint32_t)la | ((uint32_t)lb << 16);
        bf_split(va.w, ha, la); bf_split(vb.w, hb, lb);
        xh[base + 396] = (uint32_t)ha | ((uint32_t)hb << 16);
        xl[base + 396] = (uint32_t)la | ((uint32_t)lb << 16);
    }
    __syncthreads();

    const int hwbase[3] = {0, 16, 20};

    f32x4 acc0[3][3] = {}, acc1[3][3] = {};
    for (int kt = 0; kt < 8; ++kt) {
        bf16x8 bh[3], bl[3];
        #pragma unroll
        for (int mi = 0; mi < 3; ++mi) {
            if (mi < nm) {
                int woff = ((wv + 4 * mi) * 16 + row) * 256 + kt * 32 + g * 8;
                bh[mi] = *(const bf16x8*)(g_whi + woff);
                bl[mi] = *(const bf16x8*)(g_wlo + woff);
            }
        }
        bf16x8 ah0[3], al0[3], ah1[3], al1[3];
        #pragma unroll
        for (int nt = 0; nt < 3; ++nt) {
            int o2 = (hwbase[nt] + row) * 264 + kt * 32 + g * 8;
            ah0[nt] = *(const bf16x8*)(xs_s + o2);
            al0[nt] = *(const bf16x8*)(xs_s + 9504 + o2);
            ah1[nt] = *(const bf16x8*)(xs_s + 19008 + o2);
            al1[nt] = *(const bf16x8*)(xs_s + 28512 + o2);
        }
        #pragma unroll
        for (int mi = 0; mi < 3; ++mi) {
            if (mi < nm) {
                #pragma unroll
                for (int nt = 0; nt < 3; ++nt) {
                    acc0[mi][nt] = mfma16(ah0[nt], bh[mi], acc0[mi][nt]);
                    acc1[mi][nt] = mfma16(ah1[nt], bh[mi], acc1[mi][nt]);
                    acc0[mi][nt] = mfma16(al0[nt], bh[mi], acc0[mi][nt]);
                    acc1[mi][nt] = mfma16(al1[nt], bh[mi], acc1[mi][nt]);
                    acc0[mi][nt] = mfma16(ah0[nt], bl[mi], acc0[mi][nt]);
                    acc1[mi][nt] = mfma16(ah1[nt], bl[mi], acc1[mi][nt]);
                }
            }
        }
    }

    // C-write (+bias): hw = hwbase[nt]+g*4+r ; tile2 writes only g==3 (hw 32-35)
    float* cg0 = caps_g + (size_t)(2 * bb) * (160 * HWSZ);
    float* cg1 = caps_g + (size_t)(2 * bb + 1) * (160 * HWSZ);
    #pragma unroll
    for (int mi = 0; mi < 3; ++mi) {
        if (mi < nm) {
            int m = (wv + 4 * mi) * 16 + row;
            float bias = conv_b[m];
            #pragma unroll
            for (int nt = 0; nt < 3; ++nt) {
                int hw0 = hwbase[nt] + g * 4;
                if (nt < 2 || g == 3) {
                    float4 o0, o1;
                    o0.x = acc0[mi][nt][0] + bias; o1.x = acc1[mi][nt][0] + bias;
                    o0.y = acc0[mi][nt][1] + bias; o1.y = acc1[mi][nt][1] + bias;
                    o0.z = acc0[mi][nt][2] + bias; o1.z = acc1[mi][nt][2] + bias;
                    o0.w = acc0[mi][nt][3] + bias; o1.w = acc1[mi][nt][3] + bias;
                    *(float4*)(cg0 + m * HWSZ + hw0) = o0;
                    *(float4*)(cg1 + m * HWSZ + hw0) = o1;
                }
            }
        }
    }
}

// ---- route_kernel: u-transform + dynamic routing per batch element (R11-measured ~33us)
__global__ __launch_bounds__(256, 2)
void route_kernel(const float* __restrict__ caps_g, float* __restrict__ out) {
    extern __shared__ char smem[];
    float* u_t     = (float*)smem;            // [16][724]
    float* b_s     = u_t + 16 * 724;          // [720]
    float* c_s     = b_s + 720;               // [720]
    float* v_s     = c_s + 720;               // [160]
    float* scale_s = v_s + 160;               // [10]

    const int t  = threadIdx.x;
    const int bb = blockIdx.x;

    {
        const float4* cg4 = (const float4*)(caps_g + (size_t)bb * (160 * HWSZ));
        for (int task = t; task < KCAPS * PRIM; task += 256) {
            int k = task / PRIM;
            int p = task - k * PRIM;
            float4 c0 = cg4[task * 2];
            float4 c1 = cg4[task * 2 + 1];
            float pv[PD] = {c0.x, c0.y, c0.z, c0.w, c1.x, c1.y, c1.z, c1.w};
            const float4* wb = g_wtsT4 + k * (PD * 4 * PRIM) + p;
            float au[EDIM] = {};
            #pragma unroll
            for (int d = 0; d < PD; ++d) {
                #pragma unroll
                for (int e4 = 0; e4 < 4; ++e4) {
                    float4 w4 = wb[(d * 4 + e4) * PRIM];
                    au[e4 * 4 + 0] = fmaf(pv[d], w4.x, au[e4 * 4 + 0]);
                    au[e4 * 4 + 1] = fmaf(pv[d], w4.y, au[e4 * 4 + 1]);
                    au[e4 * 4 + 2] = fmaf(pv[d], w4.z, au[e4 * 4 + 2]);
                    au[e4 * 4 + 3] = fmaf(pv[d], w4.w, au[e4 * 4 + 3]);
                }
            }
            #pragma unroll
            for (int e = 0; e < EDIM; ++e) u_t[e * 724 + task] = au[e];
        }
    }
    for (int i = t; i < KCAPS * PRIM; i += 256) b_s[i] = 0.f;
    __syncthreads();

    for (int it = 0; it < 3; ++it) {
        if (t < PRIM) {
            float bv[KCAPS];
            float m = -1e30f;
            #pragma unroll
            for (int k2 = 0; k2 < KCAPS; ++k2) { bv[k2] = b_s[k2 * PRIM + t]; m = fmaxf(m, bv[k2]); }
            float sum = 0.f;
            #pragma unroll
            for (int k2 = 0; k2 < KCAPS; ++k2) { bv[k2] = __expf(bv[k2] - m); sum += bv[k2]; }
            float inv = 1.f / sum;
            #pragma unroll
            for (int k2 = 0; k2 < KCAPS; ++k2) c_s[k2 * PRIM + t] = bv[k2] * inv;
        }
        __syncthreads();

        if (t < KCAPS * EDIM) {
            int k = t >> 4, e = t & 15;
            float s = 0.f;
            const float* ur = u_t + e * 724 + k * PRIM;
            const float* cr = c_s + k * PRIM;
            for (int p = 0; p < PRIM; ++p) s = fmaf(cr[p], ur[p], s);
            v_s[t] = s;
        }
        __syncthreads();

        if (t < KCAPS) {
            float sq = 0.f;
            #pragma unroll
            for (int e = 0; e < EDIM; ++e) { float sv = v_s[t * EDIM + e]; sq = fmaf(sv, sv, sq); }
            scale_s[t] = (sq / (1.f + sq)) * rsqrtf(sq + 1e-8f);
        }
        __syncthreads();

        if (t < KCAPS * EDIM) v_s[t] *= scale_s[t >> 4];
        __syncthreads();

        if (it < 2) {
            for (int task = t; task < KCAPS * PRIM; task += 256) {
                int k = task / PRIM;
                float dot = 0.f;
                const float* vr = v_s + k * EDIM;
                #pragma unroll
                for (int e = 0; e < EDIM; ++e) dot = fmaf(u_t[e * 724 + task], vr[e], dot);
                b_s[task] += dot;
            }
            __syncthreads();
        }
    }

    if (t < KCAPS * EDIM) out[(size_t)bb * (KCAPS * EDIM) + t] = v_s[t];
}

extern "C" void kernel_launch(void* const* d_in, const int* in_sizes, int n_in,
                              void* d_out, int out_size, void* d_ws, size_t ws_size,
                              hipStream_t stream) {
    const float* x  = (const float*)d_in[0];
    const float* cw = (const float*)d_in[1];
    const float* cb = (const float*)d_in[2];
    const float* wt = (const float*)d_in[3];
    float* out = (float*)d_out;
    const int B = in_sizes[0] / (IC * HWSZ);   // 2048

    size_t capsNeed = (size_t)B * 160 * HWSZ * sizeof(float);   // 47.2 MB
    float* caps_g = nullptr;
    if (d_ws != nullptr && ws_size >= capsNeed) {
        caps_g = (float*)d_ws;
    } else {
        void* sym = nullptr;
        hipGetSymbolAddress(&sym, HIP_SYMBOL(g_caps_fallback));
        caps_g = (float*)sym;
    }

    hipLaunchKernelGGL(prep_kernel, dim3(160), dim3(256), 0, stream, cw, wt);

    hipFuncSetAttribute(reinterpret_cast<const void*>(&gemm_caps),
                        hipFuncAttributeMaxDynamicSharedMemorySize, SMEM_G);
    hipLaunchKernelGGL(gemm_caps, dim3(B / 2), dim3(256), SMEM_G, stream, x, cb, caps_g);

    hipFuncSetAttribute(reinterpret_cast<const void*>(&route_kernel),
                        hipFuncAttributeMaxDynamicSharedMemorySize, SMEM_B);
    hipLaunchKernelGGL(route_kernel, dim3(B), dim3(256), SMEM_B, stream, caps_g, out);
}

// Round 15
// 85.311 us; speedup vs baseline: 7.5893x; 1.1182x over previous
//
#include <hip/hip_runtime.h>
#include <stdint.h>

#define KCAPS 10
#define OC    16
#define IC    256
#define HWSZ  36
#define PRIM  72
#define PD    8
#define EDIM  16
#define BMAX  2048

typedef short bf16x8 __attribute__((ext_vector_type(8)));
typedef float f32x4  __attribute__((ext_vector_type(4)));

// persistent prepped data (recomputed every launch -> deterministic)
__device__ unsigned short g_whi[KCAPS * OC * IC];
__device__ unsigned short g_wlo[KCAPS * OC * IC];
__device__ float4         g_wtsT4[KCAPS * PD * 4 * PRIM];   // [k][(d*4+e4)][p]
__device__ float          g_caps_fallback[(size_t)BMAX * 160 * HWSZ];

// gemm2 LDS (76032 B), 2 batch elements (short offsets):
//   b0: xsh [0,9504) xsl [9504,19008) ; b1: xsh [19008,28512) xsl [28512,38016)
//   each plane bf16 [36][264]; n-tiles based at hw {0,16,20} -> all reads in-bounds
#define SMEM_G 76032
// route v2 LDS: u_t f32[16][724] (46336 B) | b_s[720] | c_s[720] | v_s[160] = 52736 B
#define SMEM_R (13184 * 4)

__device__ __forceinline__ void bf_split(float v, unsigned short& hb, unsigned short& lb) {
    __bf16 h = (__bf16)v;
    hb = __builtin_bit_cast(unsigned short, h);
    __bf16 l = (__bf16)(v - (float)h);
    lb = __builtin_bit_cast(unsigned short, l);
}

__device__ __forceinline__ f32x4 mfma16(bf16x8 a, bf16x8 b, f32x4 c) {
    return __builtin_amdgcn_mfma_f32_16x16x32_bf16(a, b, c, 0, 0, 0);
}

__global__ __launch_bounds__(256)
void prep_kernel(const float* __restrict__ w, const float* __restrict__ wts) {
    int i = blockIdx.x * 256 + threadIdx.x;
    if (i < KCAPS * OC * IC) {                 // 40960
        unsigned short hb, lb;
        bf_split(w[i], hb, lb);
        g_whi[i] = hb;
        g_wlo[i] = lb;
    }
    if (i < KCAPS * PD * 4 * PRIM) {           // 23040 float4 tasks
        int p = i % PRIM;
        int r = i / PRIM;
        int e4 = r & 3;
        int d  = (r >> 2) & 7;
        int k  = r >> 5;
        g_wtsT4[i] = *(const float4*)(wts + (size_t)(((k * PRIM + p) * PD + d) * EDIM + e4 * 4));
    }
}

// ---- gemm2: 2 batch elements per block, fused transpose, dual accumulators (R14-proven ~53us)
__global__ __launch_bounds__(256, 2)
void gemm_caps(const float* __restrict__ x, const float* __restrict__ conv_b,
               float* __restrict__ caps_g) {
    extern __shared__ char smem[];
    uint32_t* xs_u = (uint32_t*)smem;
    const short* xs_s = (const short*)smem;

    const int t  = threadIdx.x;
    const int bb = blockIdx.x;
    const int wv = t >> 6;
    const int ln = t & 63;
    const int row = ln & 15;
    const int g   = ln >> 4;
    const int nm  = (wv < 2) ? 3 : 2;

    for (int task = t; task < 2304; task += 256) {
        int half = (task >= 1152) ? 1 : 0;
        int tt = task - half * 1152;
        int cp = tt / 9, hq = tt - cp * 9;
        const float4* x4 = (const float4*)(x + (size_t)(2 * bb + half) * (IC * HWSZ));
        float4 va = x4[(2 * cp) * 9 + hq];
        float4 vb = x4[(2 * cp + 1) * 9 + hq];
        uint32_t* xh = xs_u + half * 9504;
        uint32_t* xl = xh + 4752;
        int base = (4 * hq) * 132 + cp;
        unsigned short ha, la, hb, lb;
        bf_split(va.x, ha, la); bf_split(vb.x, hb, lb);
        xh[base]       = (uint32_t)ha | ((uint32_t)hb << 16);
        xl[base]       = (uint32_t)la | ((uint32_t)lb << 16);
        bf_split(va.y, ha, la); bf_split(vb.y, hb, lb);
        xh[base + 132] = (uint32_t)ha | ((uint32_t)hb << 16);
        xl[base + 132] = (uint32_t)la | ((uint32_t)lb << 16);
        bf_split(va.z, ha, la); bf_split(vb.z, hb, lb);
        xh[base + 264] = (uint32_t)ha | ((uint32_t)hb << 16);
        xl[base + 264] = (uint32_t)la | ((uint32_t)lb << 16);
        bf_split(va.w, ha, la); bf_split(vb.w, hb, lb);
        xh[base + 396] = (uint32_t)ha | ((uint32_t)hb << 16);
        xl[base + 396] = (uint32_t)la | ((uint32_t)lb << 16);
    }
    __syncthreads();

    const int hwbase[3] = {0, 16, 20};

    f32x4 acc0[3][3] = {}, acc1[3][3] = {};
    for (int kt = 0; kt < 8; ++kt) {
        bf16x8 bh[3], bl[3];
        #pragma unroll
        for (int mi = 0; mi < 3; ++mi) {
            if (mi < nm) {
                int woff = ((wv + 4 * mi) * 16 + row) * 256 + kt * 32 + g * 8;
                bh[mi] = *(const bf16x8*)(g_whi + woff);
                bl[mi] = *(const bf16x8*)(g_wlo + woff);
            }
        }
        bf16x8 ah0[3], al0[3], ah1[3], al1[3];
        #pragma unroll
        for (int nt = 0; nt < 3; ++nt) {
            int o2 = (hwbase[nt] + row) * 264 + kt * 32 + g * 8;
            ah0[nt] = *(const bf16x8*)(xs_s + o2);
            al0[nt] = *(const bf16x8*)(xs_s + 9504 + o2);
            ah1[nt] = *(const bf16x8*)(xs_s + 19008 + o2);
            al1[nt] = *(const bf16x8*)(xs_s + 28512 + o2);
        }
        #pragma unroll
        for (int mi = 0; mi < 3; ++mi) {
            if (mi < nm) {
                #pragma unroll
                for (int nt = 0; nt < 3; ++nt) {
                    acc0[mi][nt] = mfma16(ah0[nt], bh[mi], acc0[mi][nt]);
                    acc1[mi][nt] = mfma16(ah1[nt], bh[mi], acc1[mi][nt]);
                    acc0[mi][nt] = mfma16(al0[nt], bh[mi], acc0[mi][nt]);
                    acc1[mi][nt] = mfma16(al1[nt], bh[mi], acc1[mi][nt]);
                    acc0[mi][nt] = mfma16(ah0[nt], bl[mi], acc0[mi][nt]);
                    acc1[mi][nt] = mfma16(ah1[nt], bl[mi], acc1[mi][nt]);
                }
            }
        }
    }

    float* cg0 = caps_g + (size_t)(2 * bb) * (160 * HWSZ);
    float* cg1 = caps_g + (size_t)(2 * bb + 1) * (160 * HWSZ);
    #pragma unroll
    for (int mi = 0; mi < 3; ++mi) {
        if (mi < nm) {
            int m = (wv + 4 * mi) * 16 + row;
            float bias = conv_b[m];
            #pragma unroll
            for (int nt = 0; nt < 3; ++nt) {
                int hw0 = hwbase[nt] + g * 4;
                if (nt < 2 || g == 3) {
                    float4 o0, o1;
                    o0.x = acc0[mi][nt][0] + bias; o1.x = acc1[mi][nt][0] + bias;
                    o0.y = acc0[mi][nt][1] + bias; o1.y = acc1[mi][nt][1] + bias;
                    o0.z = acc0[mi][nt][2] + bias; o1.z = acc1[mi][nt][2] + bias;
                    o0.w = acc0[mi][nt][3] + bias; o1.w = acc1[mi][nt][3] + bias;
                    *(float4*)(cg0 + m * HWSZ + hw0) = o0;
                    *(float4*)(cg1 + m * HWSZ + hw0) = o1;
                }
            }
        }
    }
}

// ---- route v2: 512 threads, 8 barriers, fused squash-in-s-phase, no iter-0 softmax
__global__ __launch_bounds__(512, 2)
void route_kernel(const float* __restrict__ caps_g, float* __restrict__ out) {
    extern __shared__ char smem[];
    float* u_t = (float*)smem;                // [16][724]
    float* b_s = u_t + 16 * 724;              // [720]
    float* c_s = b_s + 720;                   // [720]
    float* v_s = c_s + 720;                   // [160]

    const int t  = threadIdx.x;
    const int bb = blockIdx.x;

    // ---- u-transform: u_t[e][k*72+p] (coalesced wtsT4 reads over p)
    {
        const float4* cg4 = (const float4*)(caps_g + (size_t)bb * (160 * HWSZ));
        for (int task = t; task < KCAPS * PRIM; task += 512) {
            int k = task / PRIM;
            int p = task - k * PRIM;
            float4 c0 = cg4[task * 2];
            float4 c1 = cg4[task * 2 + 1];
            float pv[PD] = {c0.x, c0.y, c0.z, c0.w, c1.x, c1.y, c1.z, c1.w};
            const float4* wb = g_wtsT4 + k * (PD * 4 * PRIM) + p;
            float au[EDIM] = {};
            #pragma unroll
            for (int d = 0; d < PD; ++d) {
                #pragma unroll
                for (int e4 = 0; e4 < 4; ++e4) {
                    float4 w4 = wb[(d * 4 + e4) * PRIM];
                    au[e4 * 4 + 0] = fmaf(pv[d], w4.x, au[e4 * 4 + 0]);
                    au[e4 * 4 + 1] = fmaf(pv[d], w4.y, au[e4 * 4 + 1]);
                    au[e4 * 4 + 2] = fmaf(pv[d], w4.z, au[e4 * 4 + 2]);
                    au[e4 * 4 + 3] = fmaf(pv[d], w4.w, au[e4 * 4 + 3]);
                }
            }
            #pragma unroll
            for (int e = 0; e < EDIM; ++e) u_t[e * 724 + task] = au[e];
        }
    }
    __syncthreads();                          // #1 u_t visible

    // ---- iter 0: c = 0.1 exactly (softmax of b=0); s + fused squash via 16-lane shfl
    if (t < KCAPS * EDIM) {
        int k = t >> 4, e = t & 15;
        const float4* ur4 = (const float4*)(u_t + e * 724 + k * PRIM);
        float s = 0.f;
        #pragma unroll
        for (int j = 0; j < 18; ++j) {
            float4 u4 = ur4[j];
            s += (u4.x + u4.y) + (u4.z + u4.w);
        }
        s *= 0.1f;
        float q = s * s;
        q += __shfl_xor(q, 1); q += __shfl_xor(q, 2);
        q += __shfl_xor(q, 4); q += __shfl_xor(q, 8);
        v_s[t] = s * (q / (1.f + q)) * rsqrtf(q + 1e-8f);
    }
    __syncthreads();                          // #2 v_s visible

    // ---- agree 0: b = u . v
    for (int task = t; task < KCAPS * PRIM; task += 512) {
        int k = task / PRIM;
        const float* vr = v_s + k * EDIM;
        float dot = 0.f;
        #pragma unroll
        for (int e = 0; e < EDIM; ++e) dot = fmaf(u_t[e * 724 + task], vr[e], dot);
        b_s[task] = dot;
    }
    __syncthreads();                          // #3 b_s visible

    float vout = 0.f;
    #pragma unroll
    for (int it = 1; it < 3; ++it) {
        if (t < PRIM) {                       // softmax over k per primary p = t
            float bv[KCAPS];
            float m = -1e30f;
            #pragma unroll
            for (int k2 = 0; k2 < KCAPS; ++k2) { bv[k2] = b_s[k2 * PRIM + t]; m = fmaxf(m, bv[k2]); }
            float sum = 0.f;
            #pragma unroll
            for (int k2 = 0; k2 < KCAPS; ++k2) { bv[k2] = __expf(bv[k2] - m); sum += bv[k2]; }
            float inv = 1.f / sum;
            #pragma unroll
            for (int k2 = 0; k2 < KCAPS; ++k2) c_s[k2 * PRIM + t] = bv[k2] * inv;
        }
        __syncthreads();                      // c_s visible

        if (t < KCAPS * EDIM) {               // s + fused squash
            int k = t >> 4, e = t & 15;
            const float4* ur4 = (const float4*)(u_t + e * 724 + k * PRIM);
            const float4* cr4 = (const float4*)(c_s + k * PRIM);
            float s = 0.f;
            #pragma unroll
            for (int j = 0; j < 18; ++j) {
                float4 u4 = ur4[j];
                float4 c4 = cr4[j];
                s = fmaf(u4.x, c4.x, s);
                s = fmaf(u4.y, c4.y, s);
                s = fmaf(u4.z, c4.z, s);
                s = fmaf(u4.w, c4.w, s);
            }
            float q = s * s;
            q += __shfl_xor(q, 1); q += __shfl_xor(q, 2);
            q += __shfl_xor(q, 4); q += __shfl_xor(q, 8);
            float v = s * (q / (1.f + q)) * rsqrtf(q + 1e-8f);
            if (it < 2) v_s[t] = v;
            else vout = v;                    // final iter: keep in register
        }
        __syncthreads();                      // v_s visible / b_s reads done

        if (it < 2) {                         // agreement update
            for (int task = t; task < KCAPS * PRIM; task += 512) {
                int k = task / PRIM;
                const float* vr = v_s + k * EDIM;
                float dot = 0.f;
                #pragma unroll
                for (int e = 0; e < EDIM; ++e) dot = fmaf(u_t[e * 724 + task], vr[e], dot);
                b_s[task] += dot;
            }
            __syncthreads();                  // b_s updated
        }
    }

    if (t < KCAPS * EDIM) out[(size_t)bb * (KCAPS * EDIM) + t] = vout;
}

extern "C" void kernel_launch(void* const* d_in, const int* in_sizes, int n_in,
                              void* d_out, int out_size, void* d_ws, size_t ws_size,
                              hipStream_t stream) {
    const float* x  = (const float*)d_in[0];
    const float* cw = (const float*)d_in[1];
    const float* cb = (const float*)d_in[2];
    const float* wt = (const float*)d_in[3];
    float* out = (float*)d_out;
    const int B = in_sizes[0] / (IC * HWSZ);   // 2048

    size_t capsNeed = (size_t)B * 160 * HWSZ * sizeof(float);   // 47.2 MB
    float* caps_g = nullptr;
    if (d_ws != nullptr && ws_size >= capsNeed) {
        caps_g = (float*)d_ws;
    } else {
        void* sym = nullptr;
        hipGetSymbolAddress(&sym, HIP_SYMBOL(g_caps_fallback));
        caps_g = (float*)sym;
    }

    hipLaunchKernelGGL(prep_kernel, dim3(160), dim3(256), 0, stream, cw, wt);

    hipFuncSetAttribute(reinterpret_cast<const void*>(&gemm_caps),
                        hipFuncAttributeMaxDynamicSharedMemorySize, SMEM_G);
    hipLaunchKernelGGL(gemm_caps, dim3(B / 2), dim3(256), SMEM_G, stream, x, cb, caps_g);

    hipFuncSetAttribute(reinterpret_cast<const void*>(&route_kernel),
                        hipFuncAttributeMaxDynamicSharedMemorySize, SMEM_R);
    hipLaunchKernelGGL(route_kernel, dim3(B), dim3(512), SMEM_R, stream, caps_g, out);
}